// Round 1
// baseline (1544.747 us; speedup 1.0000x reference)
//
#include <hip/hip_runtime.h>
#include <cstdint>

#define BDIM 8
#define SDIM 2048
#define EDIM 256
#define HDIM 8
#define HDD 32
constexpr float QSCALE = 0.0625f; // 1/sqrt(256)

// ---------------------------------------------------------------------------
// Kernel 1: fused QKV projection.  out[r,e] = (x[r,:] . W[e,:] + b[e]) * scale
// scattered to [B,H,S,HD] layout. grid (B*S/64, 12), block 256.
// blockIdx.y: proj = y>>2 (0=q,1=k,2=v), coltile = y&3
// ---------------------------------------------------------------------------
__global__ __launch_bounds__(256) void qkv_proj(
    const float* __restrict__ x,
    const float* __restrict__ Wq, const float* __restrict__ bq,
    const float* __restrict__ Wk, const float* __restrict__ bk,
    const float* __restrict__ Wv, const float* __restrict__ bv,
    float* __restrict__ q_ws, float* __restrict__ k_ws, float* __restrict__ v_ws)
{
    const int proj = blockIdx.y >> 2;
    const int ct   = blockIdx.y & 3;
    const float* W    = proj == 0 ? Wq : (proj == 1 ? Wk : Wv);
    const float* bias = proj == 0 ? bq : (proj == 1 ? bk : bv);
    float* out        = proj == 0 ? q_ws : (proj == 1 ? k_ws : v_ws);
    const float scale = proj == 0 ? QSCALE : 1.0f;

    const int r0 = blockIdx.x * 64;
    const int c0 = ct * 64;

    __shared__ float As[16][65];
    __shared__ float Bs[16][65];

    const int t  = threadIdx.x;
    const int tx = t & 15, ty = t >> 4;

    float acc[4][4] = {};

    for (int k0 = 0; k0 < EDIM; k0 += 16) {
        const int kk = t & 15;
        const int rr = t >> 4;
        #pragma unroll
        for (int i = 0; i < 4; ++i) {
            As[kk][rr + i * 16] = x[(size_t)(r0 + rr + i * 16) * EDIM + k0 + kk];
            Bs[kk][rr + i * 16] = W[(size_t)(c0 + rr + i * 16) * EDIM + k0 + kk];
        }
        __syncthreads();
        #pragma unroll
        for (int k2 = 0; k2 < 16; ++k2) {
            float a[4], b[4];
            #pragma unroll
            for (int i = 0; i < 4; ++i) a[i] = As[k2][ty * 4 + i];
            #pragma unroll
            for (int j = 0; j < 4; ++j) b[j] = Bs[k2][tx * 4 + j];
            #pragma unroll
            for (int i = 0; i < 4; ++i)
                #pragma unroll
                for (int j = 0; j < 4; ++j)
                    acc[i][j] = fmaf(a[i], b[j], acc[i][j]);
        }
        __syncthreads();
    }

    #pragma unroll
    for (int i = 0; i < 4; ++i) {
        const int r  = r0 + ty * 4 + i;
        const int b_ = r / SDIM, s_ = r % SDIM;
        #pragma unroll
        for (int j = 0; j < 4; ++j) {
            const int e = c0 + tx * 4 + j;
            const int h = e >> 5, d = e & 31;
            const float val = (acc[i][j] + bias[e]) * scale;
            out[(((size_t)(b_ * HDIM + h)) * SDIM + s_) * HDD + d] = val;
        }
    }
}

// ---------------------------------------------------------------------------
// Kernel 2: column softmax normalizer.  Z[b,h,k] = sum_q exp(s[q,k])
// s[q,k] = Qs[q,:].K[k,:] + mask[b,q]*1e-9   (Q pre-scaled by 1/16)
// grid B*H*(S/256) = 512, block 256 (one key per thread).
// ---------------------------------------------------------------------------
__global__ __launch_bounds__(256) void col_softmax_z(
    const float* __restrict__ q_ws, const float* __restrict__ k_ws,
    const float* __restrict__ mask, float* __restrict__ z_ws)
{
    const int bh = blockIdx.x / (SDIM / 256);
    const int kc = blockIdx.x % (SDIM / 256);
    const int b_ = bh / HDIM;
    const int k  = kc * 256 + threadIdx.x;

    const float* Kbase = k_ws + ((size_t)bh * SDIM + k) * HDD;
    float krow[32];
    #pragma unroll
    for (int j = 0; j < 32; j += 4) {
        float4 v = *reinterpret_cast<const float4*>(Kbase + j);
        krow[j] = v.x; krow[j + 1] = v.y; krow[j + 2] = v.z; krow[j + 3] = v.w;
    }

    __shared__ float qs[64][32];
    __shared__ float ms[64];

    const float* Qhead = q_ws + (size_t)bh * SDIM * HDD;
    const float* mrow  = mask + (size_t)b_ * SDIM;

    float z = 0.f;
    for (int q0 = 0; q0 < SDIM; q0 += 64) {
        __syncthreads();
        {
            const int t = threadIdx.x;
            const int qr = t >> 2, part = t & 3;
            const float* src = Qhead + (size_t)(q0 + qr) * HDD + part * 8;
            float4 v0 = *reinterpret_cast<const float4*>(src);
            float4 v1 = *reinterpret_cast<const float4*>(src + 4);
            *reinterpret_cast<float4*>(&qs[qr][part * 8])     = v0;
            *reinterpret_cast<float4*>(&qs[qr][part * 8 + 4]) = v1;
            if (t < 64) ms[t] = mrow[q0 + t] * 1e-9f;
        }
        __syncthreads();
        #pragma unroll 4
        for (int qq = 0; qq < 64; ++qq) {
            float s = 0.f;
            #pragma unroll
            for (int j = 0; j < 32; ++j) s = fmaf(qs[qq][j], krow[j], s);
            s += ms[qq];
            z += __expf(s);
        }
    }
    z_ws[(size_t)bh * SDIM + k] = z;
}

// ---------------------------------------------------------------------------
// Kernel 3: O[q,d] = sum_k exp(s[q,k]) / Z[k] * V[k,d]
// grid B*H*(S/64) = 2048, block 256. 64-query tile per block.
// ---------------------------------------------------------------------------
__global__ __launch_bounds__(256) void attn_out(
    const float* __restrict__ q_ws, const float* __restrict__ k_ws,
    const float* __restrict__ v_ws, const float* __restrict__ z_ws,
    const float* __restrict__ mask, float* __restrict__ o_ws)
{
    const int bh = blockIdx.x / (SDIM / 64);
    const int qt = blockIdx.x % (SDIM / 64);
    const int b_ = bh / HDIM;
    const int q0 = qt * 64;

    __shared__ float qs[64][33];
    __shared__ float ks[64][33];
    __shared__ float vs[64][36];
    __shared__ float Ash[64][65];
    __shared__ float ms[64];
    __shared__ float rzs[64];

    const int t = threadIdx.x;

    { // stage Q tile once (scalar writes; pad 33 for conflict-free reads)
        const int qr = t >> 2, part = t & 3;
        const float* src = q_ws + ((size_t)bh * SDIM + q0 + qr) * HDD + part * 8;
        #pragma unroll
        for (int j = 0; j < 8; ++j) qs[qr][part * 8 + j] = src[j];
        if (t < 64) ms[t] = mask[(size_t)b_ * SDIM + q0 + t] * 1e-9f;
    }

    float oacc[8] = {};
    const int qb = (t & 15) * 4;      // phase-2: 4 queries
    const int kb = (t >> 4) * 4;      // phase-2: 4 keys
    const int oq = t >> 2;            // phase-3: query index
    const int dg = (t & 3) * 8;       // phase-3: d base (8 dims)

    for (int k0 = 0; k0 < SDIM; k0 += 64) {
        __syncthreads();
        { // stage K, V tiles + reciprocal Z
            const int kr = t >> 2, part = t & 3;
            const float* ksrc = k_ws + ((size_t)bh * SDIM + k0 + kr) * HDD + part * 8;
            #pragma unroll
            for (int j = 0; j < 8; ++j) ks[kr][part * 8 + j] = ksrc[j];
            const float* vsrc = v_ws + ((size_t)bh * SDIM + k0 + kr) * HDD + part * 8;
            float4 v0 = *reinterpret_cast<const float4*>(vsrc);
            float4 v1 = *reinterpret_cast<const float4*>(vsrc + 4);
            *reinterpret_cast<float4*>(&vs[kr][part * 8])     = v0;
            *reinterpret_cast<float4*>(&vs[kr][part * 8 + 4]) = v1;
            if (t < 64) rzs[t] = 1.0f / z_ws[(size_t)bh * SDIM + k0 + t];
        }
        __syncthreads();
        { // phase 2: A = exp(QK^T + m) / Z  into LDS (4x4 register tile)
            float sacc[4][4] = {};
            #pragma unroll
            for (int j = 0; j < 32; ++j) {
                float qa[4], ka[4];
                #pragma unroll
                for (int i = 0; i < 4; ++i) qa[i] = qs[qb + i][j];
                #pragma unroll
                for (int i = 0; i < 4; ++i) ka[i] = ks[kb + i][j];
                #pragma unroll
                for (int i = 0; i < 4; ++i)
                    #pragma unroll
                    for (int jj = 0; jj < 4; ++jj)
                        sacc[i][jj] = fmaf(qa[i], ka[jj], sacc[i][jj]);
            }
            #pragma unroll
            for (int i = 0; i < 4; ++i) {
                const float mq = ms[qb + i];
                #pragma unroll
                for (int jj = 0; jj < 4; ++jj)
                    Ash[qb + i][kb + jj] = __expf(sacc[i][jj] + mq) * rzs[kb + jj];
            }
        }
        __syncthreads();
        // phase 3: O += A * V
        #pragma unroll 4
        for (int k = 0; k < 64; ++k) {
            const float a = Ash[oq][k];
            float4 v0 = *reinterpret_cast<const float4*>(&vs[k][dg]);
            float4 v1 = *reinterpret_cast<const float4*>(&vs[k][dg + 4]);
            oacc[0] = fmaf(a, v0.x, oacc[0]);
            oacc[1] = fmaf(a, v0.y, oacc[1]);
            oacc[2] = fmaf(a, v0.z, oacc[2]);
            oacc[3] = fmaf(a, v0.w, oacc[3]);
            oacc[4] = fmaf(a, v1.x, oacc[4]);
            oacc[5] = fmaf(a, v1.y, oacc[5]);
            oacc[6] = fmaf(a, v1.z, oacc[6]);
            oacc[7] = fmaf(a, v1.w, oacc[7]);
        }
    }

    float* dst = o_ws + ((size_t)bh * SDIM + q0 + oq) * HDD + dg;
    #pragma unroll
    for (int j = 0; j < 8; ++j) dst[j] = oacc[j];
}

// ---------------------------------------------------------------------------
// Kernel 4: output projection. out[r,e] = ctx[r,:].Wo[e,:] + bo[e]
// ctx gathered from [B,H,S,HD]. grid (B*S/64, 4), block 256.
// ---------------------------------------------------------------------------
__global__ __launch_bounds__(256) void out_proj(
    const float* __restrict__ o_ws, const float* __restrict__ Wo,
    const float* __restrict__ bo, float* __restrict__ out)
{
    const int r0 = blockIdx.x * 64;
    const int c0 = blockIdx.y * 64;

    __shared__ float As[16][65];
    __shared__ float Bs[16][65];

    const int t  = threadIdx.x;
    const int tx = t & 15, ty = t >> 4;

    float acc[4][4] = {};

    for (int k0 = 0; k0 < EDIM; k0 += 16) {
        const int kk = t & 15;
        const int rr = t >> 4;
        const int ie = k0 + kk;           // embedding index
        const int h = ie >> 5, d = ie & 31;
        #pragma unroll
        for (int i = 0; i < 4; ++i) {
            const int r  = r0 + rr + i * 16;
            const int b_ = r / SDIM, s_ = r % SDIM;
            As[kk][rr + i * 16] = o_ws[(((size_t)(b_ * HDIM + h)) * SDIM + s_) * HDD + d];
            Bs[kk][rr + i * 16] = Wo[(size_t)(c0 + rr + i * 16) * EDIM + ie];
        }
        __syncthreads();
        #pragma unroll
        for (int k2 = 0; k2 < 16; ++k2) {
            float a[4], b[4];
            #pragma unroll
            for (int i = 0; i < 4; ++i) a[i] = As[k2][ty * 4 + i];
            #pragma unroll
            for (int j = 0; j < 4; ++j) b[j] = Bs[k2][tx * 4 + j];
            #pragma unroll
            for (int i = 0; i < 4; ++i)
                #pragma unroll
                for (int j = 0; j < 4; ++j)
                    acc[i][j] = fmaf(a[i], b[j], acc[i][j]);
        }
        __syncthreads();
    }

    #pragma unroll
    for (int i = 0; i < 4; ++i) {
        const int r = r0 + ty * 4 + i;
        #pragma unroll
        for (int j = 0; j < 4; ++j) {
            const int e = c0 + tx * 4 + j;
            out[(size_t)r * EDIM + e] = acc[i][j] + bo[e];
        }
    }
}

// ---------------------------------------------------------------------------
extern "C" void kernel_launch(void* const* d_in, const int* in_sizes, int n_in,
                              void* d_out, int out_size, void* d_ws, size_t ws_size,
                              hipStream_t stream) {
    const float* x    = (const float*)d_in[0];
    const float* mask = (const float*)d_in[1];
    const float* Wq   = (const float*)d_in[2];
    const float* bq   = (const float*)d_in[3];
    const float* Wk   = (const float*)d_in[4];
    const float* bk   = (const float*)d_in[5];
    const float* Wv   = (const float*)d_in[6];
    const float* bv   = (const float*)d_in[7];
    const float* Wo   = (const float*)d_in[8];
    const float* bo   = (const float*)d_in[9];
    float* out = (float*)d_out;

    float* ws   = (float*)d_ws;
    const size_t bse = (size_t)BDIM * SDIM * EDIM;   // 4,194,304
    float* q_ws = ws;
    float* k_ws = q_ws + bse;
    float* v_ws = k_ws + bse;
    float* o_ws = v_ws + bse;
    float* z_ws = o_ws + bse;                         // B*H*S floats

    qkv_proj<<<dim3(BDIM * SDIM / 64, 12), 256, 0, stream>>>(
        x, Wq, bq, Wk, bk, Wv, bv, q_ws, k_ws, v_ws);
    col_softmax_z<<<dim3(BDIM * HDIM * (SDIM / 256)), 256, 0, stream>>>(
        q_ws, k_ws, mask, z_ws);
    attn_out<<<dim3(BDIM * HDIM * (SDIM / 64)), 256, 0, stream>>>(
        q_ws, k_ws, v_ws, z_ws, mask, o_ws);
    out_proj<<<dim3(BDIM * SDIM / 64, EDIM / 64), 256, 0, stream>>>(
        o_ws, Wo, bo, out);
}

// Round 4
// 510.850 us; speedup vs baseline: 3.0239x; 3.0239x over previous
//
#include <hip/hip_runtime.h>
#include <cstdint>

#define BDIM 8
#define SDIM 2048
#define EDIM 256
#define HDIM 8
#define HDD 32
constexpr float QSCALE = 0.0625f; // 1/sqrt(256)

typedef __attribute__((ext_vector_type(8))) short bf16x8;
typedef __attribute__((ext_vector_type(4))) float f32x4;

__device__ __forceinline__ ushort f2bf(float f) {
    union { float f; unsigned u; } v; v.f = f;
    unsigned r = v.u + 0x7fff + ((v.u >> 16) & 1);   // RNE
    return (ushort)(r >> 16);
}

// ---------------------------------------------------------------------------
// Kernel 1: fused QKV projection (fp32 math), emits bf16 Q (pre-scaled), bf16 K
// in [bh][s][d] layout and bf16 V transposed to [bh][d][s].
// grid (B*S/64, 12), block 256.
// ---------------------------------------------------------------------------
__global__ __launch_bounds__(256) void qkv_proj(
    const float* __restrict__ x,
    const float* __restrict__ Wq, const float* __restrict__ bq,
    const float* __restrict__ Wk, const float* __restrict__ bk,
    const float* __restrict__ Wv, const float* __restrict__ bv,
    ushort* __restrict__ q_bf, ushort* __restrict__ k_bf, ushort* __restrict__ vt_bf)
{
    const int proj = blockIdx.y >> 2;
    const int ct   = blockIdx.y & 3;
    const float* W    = proj == 0 ? Wq : (proj == 1 ? Wk : Wv);
    const float* bias = proj == 0 ? bq : (proj == 1 ? bk : bv);
    const float scale = proj == 0 ? QSCALE : 1.0f;

    const int r0 = blockIdx.x * 64;
    const int c0 = ct * 64;

    __shared__ float As[16][65];
    __shared__ float Bs[16][65];

    const int t  = threadIdx.x;
    const int tx = t & 15, ty = t >> 4;

    float acc[4][4] = {};

    for (int k0 = 0; k0 < EDIM; k0 += 16) {
        const int kk = t & 15;
        const int rr = t >> 4;
        #pragma unroll
        for (int i = 0; i < 4; ++i) {
            As[kk][rr + i * 16] = x[(size_t)(r0 + rr + i * 16) * EDIM + k0 + kk];
            Bs[kk][rr + i * 16] = W[(size_t)(c0 + rr + i * 16) * EDIM + k0 + kk];
        }
        __syncthreads();
        #pragma unroll
        for (int k2 = 0; k2 < 16; ++k2) {
            float a[4], b[4];
            #pragma unroll
            for (int i = 0; i < 4; ++i) a[i] = As[k2][ty * 4 + i];
            #pragma unroll
            for (int j = 0; j < 4; ++j) b[j] = Bs[k2][tx * 4 + j];
            #pragma unroll
            for (int i = 0; i < 4; ++i)
                #pragma unroll
                for (int j = 0; j < 4; ++j)
                    acc[i][j] = fmaf(a[i], b[j], acc[i][j]);
        }
        __syncthreads();
    }

    #pragma unroll
    for (int i = 0; i < 4; ++i) {
        const int r  = r0 + ty * 4 + i;
        const int b_ = r / SDIM, s_ = r % SDIM;
        #pragma unroll
        for (int j = 0; j < 4; ++j) {
            const int e = c0 + tx * 4 + j;
            const int h = e >> 5, d = e & 31;
            const int bh = b_ * HDIM + h;
            const float val = (acc[i][j] + bias[e]) * scale;
            if (proj == 0)
                q_bf[((size_t)bh * SDIM + s_) * HDD + d] = f2bf(val);
            else if (proj == 1)
                k_bf[((size_t)bh * SDIM + s_) * HDD + d] = f2bf(val);
            else
                vt_bf[((size_t)bh * HDD + d) * SDIM + s_] = f2bf(val);
        }
    }
}

// ---------------------------------------------------------------------------
// Kernel 2: column-softmax normalizer via MFMA.
// Computes S^T tiles = mfma(K_frag, Q_frag); Z[k] = sum_q exp(s + m_q);
// stores rz = 1/Z.  grid 64*32 = 2048 blocks, 256 threads (4 waves, 16 k each).
// ---------------------------------------------------------------------------
__global__ __launch_bounds__(256) void z_pass(
    const ushort* __restrict__ q_bf, const ushort* __restrict__ k_bf,
    const float* __restrict__ mask, float* __restrict__ rz_ws)
{
    const int bh = blockIdx.x >> 5;        // SDIM/64 = 32 k-tiles per bh
    const int kt = blockIdx.x & 31;
    const int b_ = bh >> 3;
    const int t  = threadIdx.x;
    const int w  = t >> 6, l = t & 63;
    const int lr = l & 15, lg = l >> 4;

    __shared__ float ms[SDIM];             // mask*1e-9 for all q (8 KB)
    for (int i = t; i < SDIM; i += 256) ms[i] = mask[(size_t)b_ * SDIM + i] * 1e-9f;
    __syncthreads();

    // A-frag: K rows (row = lr, kdim = lg*8..lg*8+7), held across q loop
    const int krow = kt * 64 + w * 16 + lr;
    bf16x8 kfrag = *reinterpret_cast<const bf16x8*>(
        k_bf + ((size_t)bh * SDIM + krow) * HDD + lg * 8);

    const ushort* qbase = q_bf + (size_t)bh * SDIM * HDD + lg * 8;

    float zacc[4] = {0.f, 0.f, 0.f, 0.f};
    #pragma unroll 4
    for (int q0 = 0; q0 < SDIM; q0 += 16) {
        bf16x8 qfrag = *reinterpret_cast<const bf16x8*>(qbase + (size_t)(q0 + lr) * HDD);
        f32x4 d = __builtin_amdgcn_mfma_f32_16x16x32_bf16(
            kfrag, qfrag, (f32x4){0.f, 0.f, 0.f, 0.f}, 0, 0, 0);
        const float m = ms[q0 + lr];       // q col = lr
        #pragma unroll
        for (int r = 0; r < 4; ++r) zacc[r] += __expf(d[r] + m);
    }

    // reduce across the 16 q-col lanes (bits 0..3 of lane id)
    #pragma unroll
    for (int r = 0; r < 4; ++r) {
        float z = zacc[r];
        z += __shfl_xor(z, 1, 64);
        z += __shfl_xor(z, 2, 64);
        z += __shfl_xor(z, 4, 64);
        z += __shfl_xor(z, 8, 64);
        zacc[r] = z;
    }
    if (lr == 0) {
        #pragma unroll
        for (int r = 0; r < 4; ++r)
            rz_ws[(size_t)bh * SDIM + kt * 64 + w * 16 + lg * 4 + r] = 1.0f / zacc[r];
    }
}

// ---------------------------------------------------------------------------
// Kernel 3: O = (exp(QK^T + m) * rz) @ V via MFMA.
// Per wave: 16 q rows x full d=32. Attention-weight tile goes through a
// wave-private XOR-swizzled LDS buffer (no __syncthreads in k loop).
// grid 64*32 = 2048 blocks, 256 threads.
// ---------------------------------------------------------------------------
__global__ __launch_bounds__(256) void attn_out_mfma(
    const ushort* __restrict__ q_bf, const ushort* __restrict__ k_bf,
    const ushort* __restrict__ vt_bf, const float* __restrict__ rz_ws,
    const float* __restrict__ mask, float* __restrict__ o_ws)
{
    const int bh = blockIdx.x >> 5;
    const int qt = blockIdx.x & 31;
    const int b_ = bh >> 3;
    const int t  = threadIdx.x;
    const int w  = t >> 6, l = t & 63;
    const int lr = l & 15, lg = l >> 4;

    __shared__ float  rzs[SDIM];           // 8 KB: 1/Z for all k of this bh
    __shared__ ushort aw[4][1024];         // 4 x 2 KB wave-private attn tiles
    for (int i = t; i < SDIM; i += 256) rzs[i] = rz_ws[(size_t)bh * SDIM + i];
    __syncthreads();

    const int qrow0 = qt * 64 + w * 16;

    // A-frag: Q rows (row = lr), held for entire kernel
    bf16x8 qfrag = *reinterpret_cast<const bf16x8*>(
        q_bf + ((size_t)bh * SDIM + qrow0 + lr) * HDD + lg * 8);

    // mask for this lane's 4 D-rows (q = qrow0 + lg*4 + r)
    float mreg[4];
    #pragma unroll
    for (int r = 0; r < 4; ++r)
        mreg[r] = mask[(size_t)b_ * SDIM + qrow0 + lg * 4 + r] * 1e-9f;

    f32x4 oacc0 = {0.f, 0.f, 0.f, 0.f};
    f32x4 oacc1 = {0.f, 0.f, 0.f, 0.f};

    char* awp = (char*)&aw[w][0];
    const ushort* vbase = vt_bf + (size_t)bh * HDD * SDIM + (size_t)lr * SDIM;

    for (int k0 = 0; k0 < SDIM; k0 += 64) {
        // ---- QK^T: 4 sub-tiles of 16 keys ----
        #pragma unroll
        for (int kb = 0; kb < 4; ++kb) {
            bf16x8 kfrag = *reinterpret_cast<const bf16x8*>(
                k_bf + ((size_t)bh * SDIM + k0 + kb * 16 + lr) * HDD + lg * 8);
            f32x4 s = __builtin_amdgcn_mfma_f32_16x16x32_bf16(
                qfrag, kfrag, (f32x4){0.f, 0.f, 0.f, 0.f}, 0, 0, 0);
            const float rz = rzs[k0 + kb * 16 + lr];  // k col = lr
            #pragma unroll
            for (int r = 0; r < 4; ++r) {
                const float p = __expf(s[r] + mreg[r]) * rz;
                const int row = lg * 4 + r;           // q within wave tile
                int byte = row * 128 + (kb * 16 + lr) * 2;
                byte ^= (row & 7) << 4;               // XOR swizzle
                *(ushort*)(awp + byte) = f2bf(p);
            }
        }
        asm volatile("s_waitcnt lgkmcnt(0)" ::: "memory");
        // ---- PV: 2 key-chunks x 2 d-tiles ----
        #pragma unroll
        for (int kc = 0; kc < 2; ++kc) {
            int byte = lr * 128 + (kc * 32 + lg * 8) * 2;
            byte ^= (lr & 7) << 4;
            bf16x8 afrag = *(bf16x8*)(awp + byte);    // A[q=lr][8 keys]
            const ushort* vb = vbase + k0 + kc * 32 + lg * 8;
            bf16x8 v0 = *reinterpret_cast<const bf16x8*>(vb);
            bf16x8 v1 = *reinterpret_cast<const bf16x8*>(vb + (size_t)16 * SDIM);
            oacc0 = __builtin_amdgcn_mfma_f32_16x16x32_bf16(afrag, v0, oacc0, 0, 0, 0);
            oacc1 = __builtin_amdgcn_mfma_f32_16x16x32_bf16(afrag, v1, oacc1, 0, 0, 0);
        }
    }

    #pragma unroll
    for (int r = 0; r < 4; ++r) {
        float* dst = o_ws + ((size_t)bh * SDIM + qrow0 + lg * 4 + r) * HDD;
        dst[lr]      = oacc0[r];
        dst[16 + lr] = oacc1[r];
    }
}

// ---------------------------------------------------------------------------
// Kernel 4: output projection (fp32). out[r,e] = ctx[r,:].Wo[e,:] + bo[e]
// ctx gathered from o_ws [B,H,S,HD]. grid (B*S/64, 4), block 256.
// ---------------------------------------------------------------------------
__global__ __launch_bounds__(256) void out_proj(
    const float* __restrict__ o_ws, const float* __restrict__ Wo,
    const float* __restrict__ bo, float* __restrict__ out)
{
    const int r0 = blockIdx.x * 64;
    const int c0 = blockIdx.y * 64;

    __shared__ float As[16][65];
    __shared__ float Bs[16][65];

    const int t  = threadIdx.x;
    const int tx = t & 15, ty = t >> 4;

    float acc[4][4] = {};

    for (int k0 = 0; k0 < EDIM; k0 += 16) {
        const int kk = t & 15;
        const int rr = t >> 4;
        const int ie = k0 + kk;
        const int h = ie >> 5, d = ie & 31;
        #pragma unroll
        for (int i = 0; i < 4; ++i) {
            const int r  = r0 + rr + i * 16;
            const int b_ = r / SDIM, s_ = r % SDIM;
            As[kk][rr + i * 16] = o_ws[(((size_t)(b_ * HDIM + h)) * SDIM + s_) * HDD + d];
            Bs[kk][rr + i * 16] = Wo[(size_t)(c0 + rr + i * 16) * EDIM + ie];
        }
        __syncthreads();
        #pragma unroll
        for (int k2 = 0; k2 < 16; ++k2) {
            float a[4], b[4];
            #pragma unroll
            for (int i = 0; i < 4; ++i) a[i] = As[k2][ty * 4 + i];
            #pragma unroll
            for (int j = 0; j < 4; ++j) b[j] = Bs[k2][tx * 4 + j];
            #pragma unroll
            for (int i = 0; i < 4; ++i)
                #pragma unroll
                for (int j = 0; j < 4; ++j)
                    acc[i][j] = fmaf(a[i], b[j], acc[i][j]);
        }
        __syncthreads();
    }

    #pragma unroll
    for (int i = 0; i < 4; ++i) {
        const int r = r0 + ty * 4 + i;
        #pragma unroll
        for (int j = 0; j < 4; ++j) {
            const int e = c0 + tx * 4 + j;
            out[(size_t)r * EDIM + e] = acc[i][j] + bo[e];
        }
    }
}

// ---------------------------------------------------------------------------
extern "C" void kernel_launch(void* const* d_in, const int* in_sizes, int n_in,
                              void* d_out, int out_size, void* d_ws, size_t ws_size,
                              hipStream_t stream) {
    const float* x    = (const float*)d_in[0];
    const float* mask = (const float*)d_in[1];
    const float* Wq   = (const float*)d_in[2];
    const float* bq   = (const float*)d_in[3];
    const float* Wk   = (const float*)d_in[4];
    const float* bk   = (const float*)d_in[5];
    const float* Wv   = (const float*)d_in[6];
    const float* bv   = (const float*)d_in[7];
    const float* Wo   = (const float*)d_in[8];
    const float* bo   = (const float*)d_in[9];
    float* out = (float*)d_out;

    const size_t bse = (size_t)BDIM * SDIM * EDIM;   // 4,194,304 elements
    char* ws = (char*)d_ws;
    ushort* q_bf  = (ushort*)ws;                     // 8 MB
    ushort* k_bf  = (ushort*)(ws + bse * 2);         // 8 MB
    ushort* vt_bf = (ushort*)(ws + bse * 4);         // 8 MB
    float*  rz_ws = (float*)(ws + bse * 6);          // 512 KB
    float*  o_ws  = (float*)(ws + bse * 6 + (size_t)BDIM * HDIM * SDIM * 4);

    qkv_proj<<<dim3(BDIM * SDIM / 64, 12), 256, 0, stream>>>(
        x, Wq, bq, Wk, bk, Wv, bv, q_bf, k_bf, vt_bf);
    z_pass<<<dim3(BDIM * HDIM * (SDIM / 64)), 256, 0, stream>>>(
        q_bf, k_bf, mask, rz_ws);
    attn_out_mfma<<<dim3(BDIM * HDIM * (SDIM / 64)), 256, 0, stream>>>(
        q_bf, k_bf, vt_bf, rz_ws, mask, o_ws);
    out_proj<<<dim3(BDIM * SDIM / 64, EDIM / 64), 256, 0, stream>>>(
        o_ws, Wo, bo, out);
}

// Round 5
// 322.383 us; speedup vs baseline: 4.7917x; 1.5846x over previous
//
#include <hip/hip_runtime.h>
#include <cstdint>

#define BDIM 8
#define SDIM 2048
#define EDIM 256
#define HDIM 8
#define HDD 32
constexpr float QSCALE = 0.0625f; // 1/sqrt(256)

typedef __attribute__((ext_vector_type(8))) short bf16x8;
typedef __attribute__((ext_vector_type(4))) float f32x4;

__device__ __forceinline__ ushort f2bf(float f) {
    union { float f; unsigned u; } v; v.f = f;
    unsigned r = v.u + 0x7fff + ((v.u >> 16) & 1);   // RNE
    return (ushort)(r >> 16);
}
__device__ __forceinline__ float bf2f(ushort u) {
    union { unsigned u; float f; } v; v.u = ((unsigned)u) << 16;
    return v.f;
}

// ---------------------------------------------------------------------------
// Kernel 0: convert x and the 4 weight matrices to bf16.
// grid 2176 x 256: first 524288 threads handle x (8 elems each),
// next 32768 handle the 4 weights (8192 threads x 8 elems per weight).
// ---------------------------------------------------------------------------
__global__ __launch_bounds__(256) void prep_bf16(
    const float* __restrict__ x,
    const float* __restrict__ Wq, const float* __restrict__ Wk,
    const float* __restrict__ Wv, const float* __restrict__ Wo,
    ushort* __restrict__ x_bf, ushort* __restrict__ w_bf)
{
    const int tid = blockIdx.x * 256 + threadIdx.x;
    const int NX = (BDIM * SDIM * EDIM) / 8;   // 524288
    const float* src;
    ushort* dst;
    if (tid < NX) {
        src = x + (size_t)tid * 8;
        dst = x_bf + (size_t)tid * 8;
    } else {
        const int id2  = tid - NX;             // 0..32767
        const int wsel = id2 >> 13;            // 8192 threads per weight
        const int off  = (id2 & 8191) * 8;
        const float* W = wsel == 0 ? Wq : wsel == 1 ? Wk : wsel == 2 ? Wv : Wo;
        src = W + off;
        dst = w_bf + (size_t)wsel * 65536 + off;
    }
    float4 a = *(const float4*)src;
    float4 b = *(const float4*)(src + 4);
    bf16x8 o;
    o[0] = (short)f2bf(a.x); o[1] = (short)f2bf(a.y);
    o[2] = (short)f2bf(a.z); o[3] = (short)f2bf(a.w);
    o[4] = (short)f2bf(b.x); o[5] = (short)f2bf(b.y);
    o[6] = (short)f2bf(b.z); o[7] = (short)f2bf(b.w);
    *(bf16x8*)dst = o;
}

// ---------------------------------------------------------------------------
// Kernel 1: QKV projection via MFMA (LDS-free; W panels live in L1/L2).
// C[r,e'] = sum_e x[r,e]*W[e',e]; epilogue adds bias (fp32), scales Q,
// scatters to q_bf/k_bf [bh][s][d] and vt_bf [bh][d][s].
// grid (256, 12): y = proj*4 + coltile. block 256 (4 waves x 16 rows).
// ---------------------------------------------------------------------------
__global__ __launch_bounds__(256) void qkv_mfma(
    const ushort* __restrict__ x_bf, const ushort* __restrict__ w_bf,
    const float* __restrict__ bq, const float* __restrict__ bk,
    const float* __restrict__ bv,
    ushort* __restrict__ q_bf, ushort* __restrict__ k_bf, ushort* __restrict__ vt_bf)
{
    const int proj = blockIdx.y >> 2;
    const int ct   = blockIdx.y & 3;
    const ushort* W    = w_bf + (size_t)proj * 65536;
    const float*  bias = proj == 0 ? bq : (proj == 1 ? bk : bv);

    const int r0 = blockIdx.x * 64;
    const int c0 = ct * 64;
    const int t = threadIdx.x, w = t >> 6, l = t & 63;
    const int lr = l & 15, lg = l >> 4;
    const int rbase = r0 + w * 16;

    f32x4 acc[4] = {};
    const ushort* arow = x_bf + (size_t)(rbase + lr) * EDIM + lg * 8;
    #pragma unroll
    for (int kc = 0; kc < 8; ++kc) {
        bf16x8 afrag = *(const bf16x8*)(arow + kc * 32);
        #pragma unroll
        for (int tile = 0; tile < 4; ++tile) {
            bf16x8 bfrag = *(const bf16x8*)(
                W + (size_t)(c0 + tile * 16 + lr) * EDIM + kc * 32 + lg * 8);
            acc[tile] = __builtin_amdgcn_mfma_f32_16x16x32_bf16(
                afrag, bfrag, acc[tile], 0, 0, 0);
        }
    }
    #pragma unroll
    for (int tile = 0; tile < 4; ++tile) {
        const int e = c0 + tile * 16 + lr;     // output col (C/D col = lane&15)
        const float bs = bias[e];
        const int h = e >> 5, d = e & 31;
        #pragma unroll
        for (int ri = 0; ri < 4; ++ri) {
            const int r  = rbase + lg * 4 + ri; // C/D row = (lane>>4)*4 + reg
            const int b_ = r / SDIM, s_ = r % SDIM;
            const int bh = b_ * HDIM + h;
            const float val = acc[tile][ri] + bs;
            if (proj == 0)
                q_bf[((size_t)bh * SDIM + s_) * HDD + d] = f2bf(val * QSCALE);
            else if (proj == 1)
                k_bf[((size_t)bh * SDIM + s_) * HDD + d] = f2bf(val);
            else
                vt_bf[((size_t)bh * HDD + d) * SDIM + s_] = f2bf(val);
        }
    }
}

// ---------------------------------------------------------------------------
// Kernel 2: column-softmax normalizer via MFMA, then folds 1/Z into V^T
// in place (so attn_out needs no rz at all).
// Block: 128 keys (4 waves x 2 k-tiles of 16). grid 64*16 = 1024.
// ---------------------------------------------------------------------------
__global__ __launch_bounds__(256) void z_pass(
    const ushort* __restrict__ q_bf, const ushort* __restrict__ k_bf,
    const float* __restrict__ mask, ushort* __restrict__ vt_bf)
{
    const int bh = blockIdx.x >> 4;
    const int kt = blockIdx.x & 15;
    const int b_ = bh >> 3;
    const int t = threadIdx.x, w = t >> 6, l = t & 63;
    const int lr = l & 15, lg = l >> 4;

    __shared__ float ms[SDIM];   // mask*1e-9 (8 KB)
    __shared__ float zs[128];    // rz for this block's 128 keys
    for (int i = t; i < SDIM; i += 256) ms[i] = mask[(size_t)b_ * SDIM + i] * 1e-9f;
    __syncthreads();

    const int kbase = kt * 128 + w * 32;
    bf16x8 kfrag0 = *(const bf16x8*)(k_bf + ((size_t)bh * SDIM + kbase + lr) * HDD + lg * 8);
    bf16x8 kfrag1 = *(const bf16x8*)(k_bf + ((size_t)bh * SDIM + kbase + 16 + lr) * HDD + lg * 8);

    const ushort* qbase = q_bf + (size_t)bh * SDIM * HDD + lg * 8;

    float z0[4] = {}, z1[4] = {};
    #pragma unroll 4
    for (int q0 = 0; q0 < SDIM; q0 += 16) {
        bf16x8 qfrag = *(const bf16x8*)(qbase + (size_t)(q0 + lr) * HDD);
        f32x4 d0 = __builtin_amdgcn_mfma_f32_16x16x32_bf16(
            kfrag0, qfrag, (f32x4){0.f, 0.f, 0.f, 0.f}, 0, 0, 0);
        f32x4 d1 = __builtin_amdgcn_mfma_f32_16x16x32_bf16(
            kfrag1, qfrag, (f32x4){0.f, 0.f, 0.f, 0.f}, 0, 0, 0);
        const float m = ms[q0 + lr];          // q col = lane&15
        #pragma unroll
        for (int r = 0; r < 4; ++r) {
            z0[r] += __expf(d0[r] + m);
            z1[r] += __expf(d1[r] + m);
        }
    }
    #pragma unroll
    for (int r = 0; r < 4; ++r) {
        float a = z0[r], b = z1[r];
        a += __shfl_xor(a, 1, 64); b += __shfl_xor(b, 1, 64);
        a += __shfl_xor(a, 2, 64); b += __shfl_xor(b, 2, 64);
        a += __shfl_xor(a, 4, 64); b += __shfl_xor(b, 4, 64);
        a += __shfl_xor(a, 8, 64); b += __shfl_xor(b, 8, 64);
        z0[r] = a; z1[r] = b;
    }
    if (lr == 0) {
        #pragma unroll
        for (int r = 0; r < 4; ++r) {
            zs[w * 32 + lg * 4 + r]      = 1.0f / z0[r];   // D row = k-in-tile
            zs[w * 32 + 16 + lg * 4 + r] = 1.0f / z1[r];
        }
    }
    __syncthreads();

    // scale V^T columns kt*128..+127 in place: thread t -> d = t>>3, 16 keys
    const int d = t >> 3, seg = t & 7;
    ushort* p = vt_bf + ((size_t)bh * HDD + d) * SDIM + kt * 128 + seg * 16;
    bf16x8 a = *(bf16x8*)p;
    bf16x8 b = *(bf16x8*)(p + 8);
    bf16x8 oa, ob;
    #pragma unroll
    for (int j = 0; j < 8; ++j) {
        oa[j] = (short)f2bf(bf2f((ushort)a[j]) * zs[seg * 16 + j]);
        ob[j] = (short)f2bf(bf2f((ushort)b[j]) * zs[seg * 16 + 8 + j]);
    }
    *(bf16x8*)p       = oa;
    *(bf16x8*)(p + 8) = ob;
}

// ---------------------------------------------------------------------------
// Kernel 3: O = exp(QK^T + m) @ Vtilde via MFMA (V pre-scaled by 1/Z).
// Per wave: 2 q-tiles of 16 (32 q), full d=32; wave-private swizzled LDS
// for the P tiles; no __syncthreads in the k loop. grid 64*16 = 1024.
// Emits bf16 O for the MFMA out-projection.
// ---------------------------------------------------------------------------
__global__ __launch_bounds__(256) void attn_out_mfma(
    const ushort* __restrict__ q_bf, const ushort* __restrict__ k_bf,
    const ushort* __restrict__ vt_bf, const float* __restrict__ mask,
    ushort* __restrict__ o_bf)
{
    const int bh = blockIdx.x >> 4;
    const int qt = blockIdx.x & 15;
    const int b_ = bh >> 3;
    const int t = threadIdx.x, w = t >> 6, l = t & 63;
    const int lr = l & 15, lg = l >> 4;

    __shared__ ushort aw[4][2][1024];   // per-wave 2 x 2KB P tiles (16 KB)

    const int qrow0 = qt * 128 + w * 32;

    bf16x8 qfragA = *(const bf16x8*)(q_bf + ((size_t)bh * SDIM + qrow0 + lr) * HDD + lg * 8);
    bf16x8 qfragB = *(const bf16x8*)(q_bf + ((size_t)bh * SDIM + qrow0 + 16 + lr) * HDD + lg * 8);

    float mA[4], mB[4];
    #pragma unroll
    for (int r = 0; r < 4; ++r) {
        mA[r] = mask[(size_t)b_ * SDIM + qrow0 + lg * 4 + r] * 1e-9f;
        mB[r] = mask[(size_t)b_ * SDIM + qrow0 + 16 + lg * 4 + r] * 1e-9f;
    }

    f32x4 oA0 = {}, oA1 = {}, oB0 = {}, oB1 = {};

    char* awA = (char*)&aw[w][0][0];
    char* awB = (char*)&aw[w][1][0];
    const ushort* vb0 = vt_bf + ((size_t)bh * HDD + lr) * SDIM;
    const ushort* vb1 = vb0 + (size_t)16 * SDIM;
    const ushort* kbh = k_bf + (size_t)bh * SDIM * HDD + lg * 8;

    for (int k0 = 0; k0 < SDIM; k0 += 64) {
        // ---- QK^T: 4 key sub-tiles, 2 q-tiles each ----
        #pragma unroll
        for (int kb = 0; kb < 4; ++kb) {
            bf16x8 kfrag = *(const bf16x8*)(kbh + (size_t)(k0 + kb * 16 + lr) * HDD);
            f32x4 sA = __builtin_amdgcn_mfma_f32_16x16x32_bf16(
                qfragA, kfrag, (f32x4){0.f, 0.f, 0.f, 0.f}, 0, 0, 0);
            f32x4 sB = __builtin_amdgcn_mfma_f32_16x16x32_bf16(
                qfragB, kfrag, (f32x4){0.f, 0.f, 0.f, 0.f}, 0, 0, 0);
            #pragma unroll
            for (int r = 0; r < 4; ++r) {
                const int row = lg * 4 + r;
                int byte = row * 128 + (kb * 16 + lr) * 2;
                byte ^= (row & 7) << 4;                    // XOR swizzle
                *(ushort*)(awA + byte) = f2bf(__expf(sA[r] + mA[r]));
                *(ushort*)(awB + byte) = f2bf(__expf(sB[r] + mB[r]));
            }
        }
        asm volatile("s_waitcnt lgkmcnt(0)" ::: "memory");
        // ---- PV: 2 key-chunks x 2 d-tiles x 2 q-tiles ----
        #pragma unroll
        for (int kc = 0; kc < 2; ++kc) {
            int byte = lr * 128 + (kc * 32 + lg * 8) * 2;
            byte ^= (lr & 7) << 4;
            bf16x8 aA = *(bf16x8*)(awA + byte);
            bf16x8 aB = *(bf16x8*)(awB + byte);
            bf16x8 v0 = *(const bf16x8*)(vb0 + k0 + kc * 32 + lg * 8);
            bf16x8 v1 = *(const bf16x8*)(vb1 + k0 + kc * 32 + lg * 8);
            oA0 = __builtin_amdgcn_mfma_f32_16x16x32_bf16(aA, v0, oA0, 0, 0, 0);
            oA1 = __builtin_amdgcn_mfma_f32_16x16x32_bf16(aA, v1, oA1, 0, 0, 0);
            oB0 = __builtin_amdgcn_mfma_f32_16x16x32_bf16(aB, v0, oB0, 0, 0, 0);
            oB1 = __builtin_amdgcn_mfma_f32_16x16x32_bf16(aB, v1, oB1, 0, 0, 0);
        }
    }

    #pragma unroll
    for (int r = 0; r < 4; ++r) {
        ushort* dA = o_bf + ((size_t)bh * SDIM + qrow0 + lg * 4 + r) * HDD;
        dA[lr]      = f2bf(oA0[r]);
        dA[16 + lr] = f2bf(oA1[r]);
        ushort* dB = o_bf + ((size_t)bh * SDIM + qrow0 + 16 + lg * 4 + r) * HDD;
        dB[lr]      = f2bf(oB0[r]);
        dB[16 + lr] = f2bf(oB1[r]);
    }
}

// ---------------------------------------------------------------------------
// Kernel 4: output projection via MFMA. out[r,e'] = ctx[r,:].Wo[e',:] + bo[e']
// ctx read from o_bf [bh][s][d] (e-chunk kc == head kc). grid (256, 4).
// ---------------------------------------------------------------------------
__global__ __launch_bounds__(256) void out_proj_mfma(
    const ushort* __restrict__ o_bf, const ushort* __restrict__ w_bf,
    const float* __restrict__ bo, float* __restrict__ out)
{
    const ushort* Wo = w_bf + (size_t)3 * 65536;
    const int r0 = blockIdx.x * 64;
    const int c0 = blockIdx.y * 64;
    const int t = threadIdx.x, w = t >> 6, l = t & 63;
    const int lr = l & 15, lg = l >> 4;
    const int rbase = r0 + w * 16;
    const int r_ = rbase + lr;
    const int b_ = r_ / SDIM, s_ = r_ % SDIM;

    f32x4 acc[4] = {};
    #pragma unroll
    for (int kc = 0; kc < 8; ++kc) {    // e-chunk kc covers head h = kc
        bf16x8 afrag = *(const bf16x8*)(
            o_bf + (((size_t)(b_ * HDIM + kc)) * SDIM + s_) * HDD + lg * 8);
        #pragma unroll
        for (int tile = 0; tile < 4; ++tile) {
            bf16x8 bfrag = *(const bf16x8*)(
                Wo + (size_t)(c0 + tile * 16 + lr) * EDIM + kc * 32 + lg * 8);
            acc[tile] = __builtin_amdgcn_mfma_f32_16x16x32_bf16(
                afrag, bfrag, acc[tile], 0, 0, 0);
        }
    }
    #pragma unroll
    for (int tile = 0; tile < 4; ++tile) {
        const int e = c0 + tile * 16 + lr;
        const float bs = bo[e];
        #pragma unroll
        for (int ri = 0; ri < 4; ++ri) {
            const int r = rbase + lg * 4 + ri;
            out[(size_t)r * EDIM + e] = acc[tile][ri] + bs;
        }
    }
}

// ---------------------------------------------------------------------------
extern "C" void kernel_launch(void* const* d_in, const int* in_sizes, int n_in,
                              void* d_out, int out_size, void* d_ws, size_t ws_size,
                              hipStream_t stream) {
    const float* x    = (const float*)d_in[0];
    const float* mask = (const float*)d_in[1];
    const float* Wq   = (const float*)d_in[2];
    const float* bq   = (const float*)d_in[3];
    const float* Wk   = (const float*)d_in[4];
    const float* bk   = (const float*)d_in[5];
    const float* Wv   = (const float*)d_in[6];
    const float* bv   = (const float*)d_in[7];
    const float* Wo   = (const float*)d_in[8];
    const float* bo   = (const float*)d_in[9];
    float* out = (float*)d_out;

    char* ws = (char*)d_ws;
    ushort* x_bf  = (ushort*)ws;                      // 8 MB
    ushort* w_bf  = (ushort*)(ws + 8388608);          // 512 KB (Wq,Wk,Wv,Wo)
    ushort* q_bf  = (ushort*)(ws + 8912896);          // 8 MB
    ushort* k_bf  = (ushort*)(ws + 17301504);         // 8 MB
    ushort* vt_bf = (ushort*)(ws + 25690112);         // 8 MB
    ushort* o_bf  = (ushort*)(ws + 34078720);         // 8 MB  (total ~40.5 MB)

    prep_bf16<<<2176, 256, 0, stream>>>(x, Wq, Wk, Wv, Wo, x_bf, w_bf);
    qkv_mfma<<<dim3(BDIM * SDIM / 64, 12), 256, 0, stream>>>(
        x_bf, w_bf, bq, bk, bv, q_bf, k_bf, vt_bf);
    z_pass<<<dim3(BDIM * HDIM * (SDIM / 128)), 256, 0, stream>>>(
        q_bf, k_bf, mask, vt_bf);
    attn_out_mfma<<<dim3(BDIM * HDIM * (SDIM / 128)), 256, 0, stream>>>(
        q_bf, k_bf, vt_bf, mask, o_bf);
    out_proj_mfma<<<dim3(BDIM * SDIM / 64, EDIM / 64), 256, 0, stream>>>(
        o_bf, w_bf, bo, out);
}